// Round 1
// baseline (514.965 us; speedup 1.0000x reference)
//
#include <hip/hip_runtime.h>

// Tensor-product expansion: out[c,i,j,k,l] = tb[c,0,i]*tb[c,1,j]*tb[c,2,k]*tb[c,3,l]
// where tb = tensor + bias.  C=2048, N=4, L=16.  Output 2048*65536 fp32 = 512 MiB.
// Write-bandwidth bound; roofline ~85-110 us at ~5-6 TB/s store BW.

#define NC 2048
#define NL 16

typedef float f4 __attribute__((ext_vector_type(4)));

__global__ __launch_bounds__(256) void
tpe_kernel(const float* __restrict__ tensor,
           const float* __restrict__ bias,
           float* __restrict__ out) {
    __shared__ float tb[64];
    const int c = blockIdx.x;
    const int t = threadIdx.x;

    // stage tb[c,:,:] = tensor + bias (64 floats) into LDS
    if (t < 64) {
        tb[t] = tensor[c * 64 + t] + bias[c * 64 + t];
    }
    __syncthreads();

    // Per-thread fixed factors: k = (t>>2)&15, l-quad = t&3
    const int k  = (t >> 2) & 15;
    const int lq = (t & 3) * 4;
    const float ck = tb[32 + k];
    f4 v;
    v.x = ck * tb[48 + lq + 0];
    v.y = ck * tb[48 + lq + 1];
    v.z = ck * tb[48 + lq + 2];
    v.w = ck * tb[48 + lq + 3];

    float* op = out + (size_t)c * 65536;
    const int wg = t >> 6;  // wave id within block (0..3) -> j offset

    #pragma unroll
    for (int s = 0; s < 64; ++s) {
        const int i = s >> 2;
        const int j = (s * 4 + wg) & 15;
        const float ab = tb[i] * tb[16 + j];   // wave-uniform LDS broadcasts
        f4 o;
        o.x = ab * v.x;
        o.y = ab * v.y;
        o.z = ab * v.z;
        o.w = ab * v.w;
        // e = s*1024 + t*4 : lanes store 16B each, contiguous 1 KiB per wave
        __builtin_nontemporal_store(o, (f4*)(op + s * 1024 + t * 4));
    }
}

extern "C" void kernel_launch(void* const* d_in, const int* in_sizes, int n_in,
                              void* d_out, int out_size, void* d_ws, size_t ws_size,
                              hipStream_t stream) {
    const float* tensor = (const float*)d_in[0];
    const float* bias   = (const float*)d_in[1];
    float* out = (float*)d_out;
    tpe_kernel<<<NC, 256, 0, stream>>>(tensor, bias, out);
}